// Round 8
// baseline (370.405 us; speedup 1.0000x reference)
//
#include <hip/hip_runtime.h>

#define N_NODES 100000
#define N_EDGES 1600000
#define F_INPUT 256
#define H_DIM   128
#define C_DIM   40
#define NBKT    391                       // node buckets of 256: 391*256 = 100096
#define NCHK    782                       // 2048-edge hist chunks: 782*2048 = 1601536
#define NGEMM1  1563                      // 64-row tiles covering 100032 rows
#define NMEGA   1173                      // 391 gemm-blocks (782 tiles) + 782 hist
#define NSCAT   587                       // 196 gemm-blocks (392 tiles) + 391 scat
#define NP2A    587                       // 196 gemm-blocks (392 tiles) + 391 pass2a

typedef short  bf8   __attribute__((ext_vector_type(8)));
typedef float  f32x4 __attribute__((ext_vector_type(4)));
typedef float  f32x2 __attribute__((ext_vector_type(2)));
typedef unsigned short u16x8 __attribute__((ext_vector_type(8)));

static __device__ __forceinline__ unsigned short f2bf(float f) {
    union { float f; unsigned u; } v; v.f = f;
    unsigned r = v.u + 0x7FFFu + ((v.u >> 16) & 1u);
    return (unsigned short)(r >> 16);
}
static __device__ __forceinline__ f32x2 bfpair(unsigned u) {
    union { unsigned u; float f; } lo, hi;
    lo.u = u << 16; hi.u = u & 0xFFFF0000u;
    return (f32x2){lo.f, hi.f};
}

// ---------- k_pre: pack W1/W2 into MFMA B-frag layout ----------
__global__ void k_pre(const float* __restrict__ W1, const float* __restrict__ W2,
                      unsigned short* Wp1, unsigned short* Wp2) {
    int idx = blockIdx.x * 256 + threadIdx.x;
    if (idx < 32768) {       // 8 nt * 8 ks * 64 * 8
        int j = idx & 7, lane = (idx >> 3) & 63, ks = (idx >> 9) & 7, nt = idx >> 12;
        int m = lane & 15, q = lane >> 4;
        Wp1[idx] = f2bf(W1[(ks * 32 + q * 8 + j) * H_DIM + nt * 16 + m]);
    }
    int idx2 = idx - 32768;  // 3 nt * 4 ks * 64 * 8 = 6144
    if (idx2 >= 0 && idx2 < 6144) {
        int j = idx2 & 7, lane = (idx2 >> 3) & 63, ks = (idx2 >> 9) & 3, nt = idx2 >> 11;
        int m = lane & 15, q = lane >> 4;
        int n = nt * 16 + m;
        Wp2[idx2] = (n < C_DIM) ? f2bf(W2[(ks * 32 + q * 8 + j) * C_DIM + n]) : (unsigned short)0;
    }
}

// ---------- shared gemm role: two 64-row tiles per 512-thr block, 96 KB LDS ----------
// h (UNSCALED bf16) = x @ W1. Wp staged in LDS; x loads hoisted.
static __device__ __forceinline__ void gemm_role(
        int tileBase, int tid, char* smem,
        const float* __restrict__ x, const unsigned short* __restrict__ Wp,
        unsigned short* __restrict__ h) {
    unsigned short* sWp = (unsigned short*)smem;              // 64 KB
    unsigned short* lds_out = (unsigned short*)(smem + 65536); // 32 KB (2 tiles)
    int sub = tid >> 8;                 // 0/1: which tile
    int t256 = tid & 255;
    int wave = t256 >> 6, lane = t256 & 63;
    int m = lane & 15, q = lane >> 4;
    int tile = tileBase + sub; if (tile >= NGEMM1) tile = NGEMM1 - 1;
    int rowA = tile * 64 + wave * 16 + m; if (rowA >= N_NODES) rowA = N_NODES - 1;
    const float* xr = x + (long)rowA * F_INPUT + q * 8;

    float4 xv[16];
#pragma unroll
    for (int ks = 0; ks < 8; ks++) {
        xv[2 * ks]     = *(const float4*)(xr + ks * 32);
        xv[2 * ks + 1] = *(const float4*)(xr + ks * 32 + 4);
    }
#pragma unroll
    for (int it = 0; it < 8; it++) {    // 512 thr x 8 iters x 16 B = 64 KB
        int idx = (it * 512 + tid) * 8;
        *(u16x8*)(sWp + idx) = *(const u16x8*)(Wp + idx);
    }
    __syncthreads();

    f32x4 acc[8];
#pragma unroll
    for (int i = 0; i < 8; i++) acc[i] = (f32x4){0.f, 0.f, 0.f, 0.f};
#pragma unroll
    for (int ks = 0; ks < 8; ks++) {
        float4 a0 = xv[2 * ks], a1 = xv[2 * ks + 1];
        bf8 a;
        a[0] = (short)f2bf(a0.x); a[1] = (short)f2bf(a0.y);
        a[2] = (short)f2bf(a0.z); a[3] = (short)f2bf(a0.w);
        a[4] = (short)f2bf(a1.x); a[5] = (short)f2bf(a1.y);
        a[6] = (short)f2bf(a1.z); a[7] = (short)f2bf(a1.w);
#pragma unroll
        for (int nt = 0; nt < 8; nt++) {
            bf8 bb = *(const bf8*)(sWp + (((nt * 8 + ks) * 64 + lane) << 3));
            acc[nt] = __builtin_amdgcn_mfma_f32_16x16x32_bf16(a, bb, acc[nt], 0, 0, 0);
        }
    }
    unsigned short* ldsT = lds_out + sub * (64 * H_DIM);
    int lrow = wave * 16 + q * 4;
#pragma unroll
    for (int nt = 0; nt < 8; nt++)
#pragma unroll
        for (int r = 0; r < 4; r++)
            ldsT[(lrow + r) * H_DIM + nt * 16 + m] = f2bf(acc[nt][r]);
    __syncthreads();
    int valid = N_NODES - tile * 64; if (valid > 64) valid = 64;
    unsigned short* gbase = h + (size_t)tile * 64 * H_DIM;
#pragma unroll
    for (int i = 0; i < 4; i++) {
        int idx = (i * 256 + t256) * 8;
        if (idx < valid * H_DIM)
            *(u16x8*)(gbase + idx) = *(const u16x8*)(ldsT + idx);
    }
}

// ---------- k_mega: gemm role ∪ hist role (2048 edges, 512 thr) ----------
__global__ __launch_bounds__(512, 1) void k_mega(
        const float* __restrict__ x, const unsigned short* __restrict__ Wp,
        unsigned short* __restrict__ h,
        const int* __restrict__ col, unsigned* __restrict__ histG) {
    __shared__ __align__(16) char smem[98304];
    int b = blockIdx.x, t = threadIdx.x;
    if (b % 3 == 0) { gemm_role(2 * (b / 3), t, smem, x, Wp, h); return; }
    // hist role
    unsigned* histL = (unsigned*)smem;
    int chunk = b - b / 3 - 1;                        // 0..781
    for (int i = t; i < NBKT; i += 512) histL[i] = 0;
    __syncthreads();
    int e0 = chunk * 2048 + t;
#pragma unroll
    for (int k = 0; k < 4; k++) {
        int e = e0 + k * 512;
        if (e < N_EDGES) atomicAdd(&histL[col[e] >> 8], 1u);
    }
    __syncthreads();
    for (int i = t; i < NBKT; i += 512) histG[(size_t)i * NCHK + chunk] = histL[i];
}

// ---------- scanB: per-bucket exclusive scan over its 782 chunk counts ----------
__global__ void k_scanB(unsigned* histG, unsigned* bktTotal) {
    __shared__ unsigned s[256];
    int B = blockIdx.x, t = threadIdx.x;
    unsigned carry = 0;
    for (int c0 = 0; c0 < NCHK; c0 += 256) {
        int idx = c0 + t;
        unsigned v = (idx < NCHK) ? histG[(size_t)B * NCHK + idx] : 0;
        s[t] = v; __syncthreads();
        for (int off = 1; off < 256; off <<= 1) {
            unsigned u = (t >= off) ? s[t - off] : 0;
            __syncthreads();
            s[t] += u;
            __syncthreads();
        }
        if (idx < NCHK) histG[(size_t)B * NCHK + idx] = s[t] - v + carry;
        unsigned tot = s[255];
        __syncthreads();
        carry += tot;
    }
    if (t == 0) bktTotal[B] = carry;
}

// ---------- scanC: exclusive scan of 391 bucket totals -> bucketBase[392] ----------
__global__ void k_scanC(const unsigned* __restrict__ bktTotal, unsigned* bucketBase) {
    __shared__ unsigned s[256];
    int t = threadIdx.x;
    unsigned carry = 0;
    for (int c0 = 0; c0 < NBKT; c0 += 256) {
        int idx = c0 + t;
        unsigned v = (idx < NBKT) ? bktTotal[idx] : 0;
        s[t] = v; __syncthreads();
        for (int off = 1; off < 256; off <<= 1) {
            unsigned u = (t >= off) ? s[t - off] : 0;
            __syncthreads();
            s[t] += u;
            __syncthreads();
        }
        if (idx < NBKT) bucketBase[idx] = s[t] - v + carry;
        unsigned tot = s[255];
        __syncthreads();
        carry += tot;
    }
    if (t == 0) bucketBase[NBKT] = carry;   // == N_EDGES
}

// ---------- k_scat1: gemm role ∪ bucket-grouped scatter (4096 edges/block) ----------
// rec = { (row<<8)|col_local , ea_bits }
__global__ __launch_bounds__(512, 1) void k_scat1(
        const int* __restrict__ row, const int* __restrict__ col,
        const float* __restrict__ ea,
        const unsigned* __restrict__ histG,
        const unsigned* __restrict__ bucketBase,
        int2* __restrict__ recs,
        const float* __restrict__ x, const unsigned short* __restrict__ Wp,
        unsigned short* __restrict__ h) {
    __shared__ __align__(16) char smem[98304];
    int b = blockIdx.x, t = threadIdx.x;
    if (b % 3 == 0) { gemm_role(782 + 2 * (b / 3), t, smem, x, Wp, h); return; }
    unsigned* base_l = (unsigned*)smem;           // NBKT
    unsigned* cursor = base_l + NBKT;             // NBKT
    int blk = b - b / 3 - 1;                      // 0..390
    for (int i = t; i < NBKT; i += 512) {
        base_l[i] = bucketBase[i] + histG[(size_t)i * NCHK + blk * 2];
        cursor[i] = 0;
    }
    __syncthreads();
    int e0 = blk * 4096 + t;
#pragma unroll
    for (int k = 0; k < 8; k++) {
        int e = e0 + k * 512;
        if (e < N_EDGES) {
            int c = col[e];
            int bkt = c >> 8;
            unsigned r = atomicAdd(&cursor[bkt], 1u);
            int pos = (int)(base_l[bkt] + r);
            recs[pos] = make_int2((row[e] << 8) | (c & 255), __float_as_int(ea[e]));
        }
    }
}

// ---------- k_pass2a: gemm role ∪ per-bucket count+wsum -> start/cnt/dinv ----------
__global__ __launch_bounds__(512, 1) void k_pass2a(
        const int2* __restrict__ recs,
        const unsigned* __restrict__ bucketBase,
        int* __restrict__ start, int* __restrict__ cnt, float* __restrict__ dinv,
        const float* __restrict__ x, const unsigned short* __restrict__ Wp,
        unsigned short* __restrict__ h) {
    __shared__ __align__(16) char smem[98304];
    int b = blockIdx.x, t = threadIdx.x;
    if (b % 3 == 0) { gemm_role(1174 + 2 * (b / 3), t, smem, x, Wp, h); return; }
    unsigned* cntL = (unsigned*)smem;     // 256
    unsigned* wsL  = cntL + 256;          // 256
    unsigned* s    = wsL + 256;           // 256
    int B = b - b / 3 - 1;                // 0..390
    if (t < 256) { cntL[t] = 0; wsL[t] = 0; }
    __syncthreads();
    int lo = (int)bucketBase[B], hi = (int)bucketBase[B + 1];
    for (int i = lo + t; i < hi; i += 512) {
        int2 rc = recs[i];
        int cl = rc.x & 255;
        atomicAdd(&cntL[cl], 1u);
        unsigned q = __float2uint_rn(__int_as_float(rc.y) * 65536.0f);
        atomicAdd(&wsL[cl], q);
    }
    __syncthreads();
    unsigned v = 0;
    if (t < 256) { v = cntL[t]; s[t] = v; }
    __syncthreads();
    for (int off = 1; off < 256; off <<= 1) {
        unsigned u = 0;
        if (t < 256 && t >= (unsigned)off) u = s[t - off];
        __syncthreads();
        if (t < 256) s[t] += u;
        __syncthreads();
    }
    if (t < 256) {
        int node = B * 256 + t;
        if (node < N_NODES) {
            start[node] = lo + (int)(s[t] - v);
            cnt[node] = (int)v;
            dinv[node] = rsqrtf((float)(65536u + wsL[t]) * (1.0f / 65536.0f));
        }
    }
}

// ---------- k_pass2b: final CSR slots, w = ea * dinv[row] (dinv L2-resident) ----------
__global__ void k_pass2b(const int2* __restrict__ recs,
                         const unsigned* __restrict__ bucketBase,
                         const int* __restrict__ start,
                         const float* __restrict__ dinv,
                         int2* __restrict__ csr) {
    __shared__ int startL[256];
    __shared__ unsigned cur[256];
    int B = blockIdx.x, t = threadIdx.x;
    if (t < 256) {
        int node = B * 256 + t;
        startL[t] = (node < N_NODES) ? start[node] : 0;
        cur[t] = 0;
    }
    __syncthreads();
    int lo = (int)bucketBase[B], hi = (int)bucketBase[B + 1];
    for (int i = lo + t; i < hi; i += 512) {
        int2 rc = recs[i];
        int cl = rc.x & 255;
        int rw = rc.x >> 8;
        float w = __int_as_float(rc.y) * dinv[rw];
        unsigned r = atomicAdd(&cur[cl], 1u);
        csr[startL[cl] + (int)r] = make_int2(rw, __float_as_int(w));
    }
}

// ---------- agg1: wave/node, lane owns 2 dims; csr w = ea*dinv[row] ----------
// h1[c] = relu(di*(di*h[c] + sum w_e*h[row_e]) + b1)
__global__ __launch_bounds__(256) void k_agg1(
        const unsigned* __restrict__ hw, const int2* __restrict__ csr,
        const int* __restrict__ start, const int* __restrict__ cnt,
        const float* __restrict__ dinv, const float* __restrict__ b1,
        unsigned* __restrict__ h1w) {
    int c = blockIdx.x * 4 + (threadIdx.x >> 6);
    int lane = threadIdx.x & 63;
    if (c >= N_NODES) return;
    float di = dinv[c];
    int su = __builtin_amdgcn_readfirstlane(start[c]);
    int n  = __builtin_amdgcn_readfirstlane(cnt[c]);
    f32x2 acc;
    {
        f32x2 sp = bfpair(hw[(size_t)c * 64 + lane]);
        acc = (f32x2){di, di} * sp;
    }
    int i = 0;
    for (; i + 4 <= n; i += 4) {
        int2 p0 = csr[su + i], p1 = csr[su + i + 1];
        int2 p2 = csr[su + i + 2], p3 = csr[su + i + 3];
        int r0 = __builtin_amdgcn_readfirstlane(p0.x);
        int r1 = __builtin_amdgcn_readfirstlane(p1.x);
        int r2 = __builtin_amdgcn_readfirstlane(p2.x);
        int r3 = __builtin_amdgcn_readfirstlane(p3.x);
        float w0 = __int_as_float(__builtin_amdgcn_readfirstlane(p0.y));
        float w1 = __int_as_float(__builtin_amdgcn_readfirstlane(p1.y));
        float w2 = __int_as_float(__builtin_amdgcn_readfirstlane(p2.y));
        float w3 = __int_as_float(__builtin_amdgcn_readfirstlane(p3.y));
        unsigned a0 = hw[(size_t)r0 * 64 + lane];
        unsigned a1 = hw[(size_t)r1 * 64 + lane];
        unsigned a2 = hw[(size_t)r2 * 64 + lane];
        unsigned a3 = hw[(size_t)r3 * 64 + lane];
        acc += (f32x2){w0, w0} * bfpair(a0);
        acc += (f32x2){w1, w1} * bfpair(a1);
        acc += (f32x2){w2, w2} * bfpair(a2);
        acc += (f32x2){w3, w3} * bfpair(a3);
    }
    for (; i < n; i++) {
        int2 p = csr[su + i];
        int r = __builtin_amdgcn_readfirstlane(p.x);
        float w = __int_as_float(__builtin_amdgcn_readfirstlane(p.y));
        unsigned a = hw[(size_t)r * 64 + lane];
        acc += (f32x2){w, w} * bfpair(a);
    }
    float2 bb = ((const float2*)b1)[lane];
    float o0 = fmaxf(di * acc.x + bb.x, 0.f);
    float o1 = fmaxf(di * acc.y + bb.y, 0.f);
    h1w[(size_t)c * 64 + lane] = (unsigned)f2bf(o0) | ((unsigned)f2bf(o1) << 16);
}

// ---------- GEMM2: h2 (UNSCALED bf16) = h1 @ W2, PADDED rows (64 shorts/128B) ----
__global__ __launch_bounds__(256, 4) void k_gemm2(const unsigned short* __restrict__ h1,
                        const unsigned short* __restrict__ Wp,
                        unsigned short* __restrict__ h2) {
    __shared__ unsigned short lds_out[64 * C_DIM];
    int tid = threadIdx.x;
    int wave = tid >> 6, lane = tid & 63;
    int m = lane & 15, q = lane >> 4;
    int row0 = blockIdx.x * 64 + wave * 16;
    int rowA = row0 + m; if (rowA >= N_NODES) rowA = N_NODES - 1;

    f32x4 acc[3];
#pragma unroll
    for (int i = 0; i < 3; i++) acc[i] = (f32x4){0.f, 0.f, 0.f, 0.f};
    const unsigned short* hr = h1 + (long)rowA * H_DIM + q * 8;
#pragma unroll
    for (int ks = 0; ks < 4; ks++) {
        bf8 a = *(const bf8*)(hr + ks * 32);
#pragma unroll
        for (int nt = 0; nt < 3; nt++) {
            bf8 b = *(const bf8*)(Wp + (((nt * 4 + ks) * 64 + lane) << 3));
            acc[nt] = __builtin_amdgcn_mfma_f32_16x16x32_bf16(a, b, acc[nt], 0, 0, 0);
        }
    }
    int lrow = wave * 16 + q * 4;
#pragma unroll
    for (int nt = 0; nt < 3; nt++)
#pragma unroll
        for (int r = 0; r < 4; r++) {
            int colo = nt * 16 + m;
            if (colo < C_DIM)
                lds_out[(lrow + r) * C_DIM + colo] = f2bf(acc[nt][r]);
        }
    __syncthreads();
    int valid = N_NODES - blockIdx.x * 64; if (valid > 64) valid = 64;
    unsigned short* gbase = h2 + (size_t)blockIdx.x * 64 * 64;   // stride 64 shorts
    int total10 = valid * 10;                                     // 10 uint2 per row
    for (int i = tid; i < total10; i += 256) {
        int rw = i / 10, part = i - rw * 10;
        *(uint2*)(gbase + rw * 64 + part * 4) = *(const uint2*)(lds_out + rw * C_DIM + part * 4);
    }
}

// ---------- agg2 + bias + log_softmax: padded h2, csr w = ea*dinv[row] ----------
// out = log_softmax(di*(di*g[c] + sum w_e*g[row_e]) + b2)
__global__ void k_agg2(const unsigned short* __restrict__ h2, const int2* __restrict__ csr,
                       const int* __restrict__ start, const int* __restrict__ cnt,
                       const float* __restrict__ dinv, const float* __restrict__ b2,
                       float* __restrict__ out) {
    int c = (blockIdx.x * blockDim.x + threadIdx.x) >> 6;
    int lane = threadIdx.x & 63;
    if (c >= N_NODES) return;
    int eg = lane >> 3, cl = lane & 7;
    float di = dinv[c];
    int s = start[c];
    int n = cnt[c];

    float w[3]; int r[3];
#pragma unroll
    for (int t = 0; t < 3; t++) {
        int i = eg + 8 * t;
        int2 p = csr[s + ((i < n) ? i : 0)];
        bool val = (i < n);
        r[t] = val ? p.x : c;
        w[t] = val ? __int_as_float(p.y) : 0.f;
    }
    uint4 gv[3] = {{0,0,0,0},{0,0,0,0},{0,0,0,0}};
    uint4 selfv = {0, 0, 0, 0};
    if (cl < 5) {
#pragma unroll
        for (int t = 0; t < 3; t++)
            gv[t] = *(const uint4*)(h2 + (long)r[t] * 64 + cl * 8);
        if (eg == 0) selfv = *(const uint4*)(h2 + (long)c * 64 + cl * 8);
    }
    f32x2 acc[4];
#pragma unroll
    for (int k = 0; k < 4; k++) acc[k] = (f32x2){0.f, 0.f};
    {
        unsigned sv[4] = {selfv.x, selfv.y, selfv.z, selfv.w};
        f32x2 dd = (f32x2){di, di};
        if (eg == 0 && cl < 5)
#pragma unroll
            for (int k = 0; k < 4; k++) acc[k] += dd * bfpair(sv[k]);
    }
#pragma unroll
    for (int t = 0; t < 3; t++) {
        unsigned vv[4] = {gv[t].x, gv[t].y, gv[t].z, gv[t].w};
        f32x2 ww = (f32x2){w[t], w[t]};
#pragma unroll
        for (int k = 0; k < 4; k++) acc[k] += ww * bfpair(vv[k]);
    }
    for (int i = 24 + eg; i < n; i += 8) {
        int2 p = csr[s + i];
        if (cl < 5) {
            uint4 v4 = *(const uint4*)(h2 + (long)p.x * 64 + cl * 8);
            unsigned vv[4] = {v4.x, v4.y, v4.z, v4.w};
            float wt = __int_as_float(p.y);
            f32x2 ww = (f32x2){wt, wt};
#pragma unroll
            for (int k = 0; k < 4; k++) acc[k] += ww * bfpair(vv[k]);
        }
    }
#pragma unroll
    for (int k = 0; k < 4; k++) {
        acc[k].x += __shfl_xor(acc[k].x, 8);  acc[k].y += __shfl_xor(acc[k].y, 8);
        acc[k].x += __shfl_xor(acc[k].x, 16); acc[k].y += __shfl_xor(acc[k].y, 16);
        acc[k].x += __shfl_xor(acc[k].x, 32); acc[k].y += __shfl_xor(acc[k].y, 32);
    }
    float v[8];
    float lm = -INFINITY;
    if (cl < 5) {
#pragma unroll
        for (int k = 0; k < 4; k++) {
            v[2 * k]     = di * acc[k].x + b2[cl * 8 + 2 * k];
            v[2 * k + 1] = di * acc[k].y + b2[cl * 8 + 2 * k + 1];
            lm = fmaxf(lm, fmaxf(v[2 * k], v[2 * k + 1]));
        }
    }
    lm = fmaxf(lm, __shfl_xor(lm, 1));
    lm = fmaxf(lm, __shfl_xor(lm, 2));
    lm = fmaxf(lm, __shfl_xor(lm, 4));
    float ls = 0.f;
    if (cl < 5) {
#pragma unroll
        for (int j = 0; j < 8; j++) ls += __expf(v[j] - lm);
    }
    ls += __shfl_xor(ls, 1);
    ls += __shfl_xor(ls, 2);
    ls += __shfl_xor(ls, 4);
    if (eg == 0 && cl < 5) {
        float lsm = lm + logf(ls);
        f32x4 o0, o1;
#pragma unroll
        for (int j = 0; j < 4; j++) { o0[j] = v[j] - lsm; o1[j] = v[j + 4] - lsm; }
        *(f32x4*)(out + (long)c * C_DIM + cl * 8)     = o0;
        *(f32x4*)(out + (long)c * C_DIM + cl * 8 + 4) = o1;
    }
}

extern "C" void kernel_launch(void* const* d_in, const int* in_sizes, int n_in,
                              void* d_out, int out_size, void* d_ws, size_t ws_size,
                              hipStream_t stream) {
    const float* x  = (const float*)d_in[0];
    const int*   ei = (const int*)d_in[1];
    const float* ea = (const float*)d_in[2];
    const float* W1 = (const float*)d_in[3];
    const float* b1 = (const float*)d_in[4];
    const float* W2 = (const float*)d_in[5];
    const float* b2 = (const float*)d_in[6];
    const int* row = ei;
    const int* col = ei + N_EDGES;

    char* ws = (char*)d_ws;
    size_t off = 0;
    auto alloc = [&](size_t bytes) -> void* {
        void* p = ws + off;
        off = (off + bytes + 255) & ~(size_t)255;
        return p;
    };
    unsigned*       histG   = (unsigned*)alloc((size_t)NBKT * NCHK * 4);  // 1.2 MB
    unsigned*       bktTot  = (unsigned*)alloc((size_t)NBKT * 4);
    unsigned*       bktBase = (unsigned*)alloc((size_t)(NBKT + 1) * 4);
    int*            start   = (int*)alloc((size_t)N_NODES * 4);
    int*            cnt     = (int*)alloc((size_t)N_NODES * 4);
    float*          dinv    = (float*)alloc((size_t)N_NODES * 4);
    int2*           recs    = (int2*)alloc((size_t)N_EDGES * 8);
    int2*           csr     = (int2*)alloc((size_t)(N_EDGES + 8) * 8); // +pad, NOT last
    unsigned short* Wp1     = (unsigned short*)alloc(32768 * 2);
    unsigned short* Wp2     = (unsigned short*)alloc(6144 * 2);
    unsigned short* h       = (unsigned short*)alloc((size_t)(N_NODES + 64) * H_DIM * 2);
    unsigned short* h1      = (unsigned short*)alloc((size_t)N_NODES * H_DIM * 2);
    unsigned short* h2      = (unsigned short*)alloc((size_t)(N_NODES + 64) * 64 * 2); // padded

    k_pre<<<152, 256, 0, stream>>>(W1, W2, Wp1, Wp2);
    k_mega<<<NMEGA, 512, 0, stream>>>(x, Wp1, h, col, histG);
    k_scanB<<<NBKT, 256, 0, stream>>>(histG, bktTot);
    k_scanC<<<1, 256, 0, stream>>>(bktTot, bktBase);
    k_scat1<<<NSCAT, 512, 0, stream>>>(row, col, ea, histG, bktBase, recs, x, Wp1, h);
    k_pass2a<<<NP2A, 512, 0, stream>>>(recs, bktBase, start, cnt, dinv, x, Wp1, h);
    k_pass2b<<<NBKT, 512, 0, stream>>>(recs, bktBase, start, dinv, csr);
    k_agg1<<<N_NODES / 4, 256, 0, stream>>>((const unsigned*)h, csr, start, cnt, dinv, b1,
                                            (unsigned*)h1);
    k_gemm2<<<(N_NODES + 63) / 64, 256, 0, stream>>>(h1, Wp2, h2);
    k_agg2<<<N_NODES / 4, 256, 0, stream>>>(h2, csr, start, cnt, dinv, b2, (float*)d_out);
}

// Round 9
// 361.279 us; speedup vs baseline: 1.0253x; 1.0253x over previous
//
#include <hip/hip_runtime.h>

#define N_NODES 100000
#define N_EDGES 1600000
#define F_INPUT 256
#define H_DIM   128
#define C_DIM   40
#define NBKT    391                       // node buckets of 256: 391*256 = 100096
#define NCHK    1563                      // fine 1024-edge chunks (hist/scan granularity)
#define NSC1    391                       // scat1 blocks: 4096 edges = 4 fine chunks each
#define NGEMM1  1563                      // 64-row tiles covering 100032 rows
#define NPREB   152                       // W-pack blocks in k_preh

typedef short  bf8   __attribute__((ext_vector_type(8)));
typedef float  f32x4 __attribute__((ext_vector_type(4)));
typedef float  f32x2 __attribute__((ext_vector_type(2)));
typedef unsigned short u16x8 __attribute__((ext_vector_type(8)));

static __device__ __forceinline__ unsigned short f2bf(float f) {
    union { float f; unsigned u; } v; v.f = f;
    unsigned r = v.u + 0x7FFFu + ((v.u >> 16) & 1u);
    return (unsigned short)(r >> 16);
}
static __device__ __forceinline__ f32x2 bfpair(unsigned u) {
    union { unsigned u; float f; } lo, hi;
    lo.u = u << 16; hi.u = u & 0xFFFF0000u;
    return (f32x2){lo.f, hi.f};
}

// ---------- k_preh: W1/W2 B-frag pack  ∪  bucket histogram (fine chunks) ----------
__global__ void k_preh(const float* __restrict__ W1, const float* __restrict__ W2,
                       unsigned short* Wp1, unsigned short* Wp2,
                       const int* __restrict__ col, unsigned* __restrict__ histG) {
    int tid = threadIdx.x;
    if (blockIdx.x >= NPREB) {
        __shared__ unsigned histL[NBKT];
        int chunk = blockIdx.x - NPREB;
        for (int i = tid; i < NBKT; i += 256) histL[i] = 0;
        __syncthreads();
        int e0 = chunk * 1024 + tid;
#pragma unroll
        for (int k = 0; k < 4; k++) {
            int e = e0 + k * 256;
            if (e < N_EDGES) atomicAdd(&histL[col[e] >> 8], 1u);
        }
        __syncthreads();
        for (int i = tid; i < NBKT; i += 256) histG[(size_t)i * NCHK + chunk] = histL[i];
        return;
    }
    int idx = blockIdx.x * 256 + tid;
    if (idx < 32768) {       // 8 nt * 8 ks * 64 * 8
        int j = idx & 7, lane = (idx >> 3) & 63, ks = (idx >> 9) & 7, nt = idx >> 12;
        int m = lane & 15, q = lane >> 4;
        Wp1[idx] = f2bf(W1[(ks * 32 + q * 8 + j) * H_DIM + nt * 16 + m]);
    }
    int idx2 = idx - 32768;  // 3 nt * 4 ks * 64 * 8 = 6144
    if (idx2 >= 0 && idx2 < 6144) {
        int j = idx2 & 7, lane = (idx2 >> 3) & 63, ks = (idx2 >> 9) & 3, nt = idx2 >> 11;
        int m = lane & 15, q = lane >> 4;
        int n = nt * 16 + m;
        Wp2[idx2] = (n < C_DIM) ? f2bf(W2[(ks * 32 + q * 8 + j) * C_DIM + n]) : (unsigned short)0;
    }
}

// ---------- scanB: per-bucket exclusive scan over its 1563 fine-chunk counts ----------
__global__ void k_scanB(unsigned* histG, unsigned* bktTotal) {
    __shared__ unsigned s[256];
    int B = blockIdx.x, t = threadIdx.x;
    unsigned carry = 0;
    for (int c0 = 0; c0 < NCHK; c0 += 256) {
        int idx = c0 + t;
        unsigned v = (idx < NCHK) ? histG[(size_t)B * NCHK + idx] : 0;
        s[t] = v; __syncthreads();
        for (int off = 1; off < 256; off <<= 1) {
            unsigned u = (t >= off) ? s[t - off] : 0;
            __syncthreads();
            s[t] += u;
            __syncthreads();
        }
        if (idx < NCHK) histG[(size_t)B * NCHK + idx] = s[t] - v + carry;
        unsigned tot = s[255];
        __syncthreads();
        carry += tot;
    }
    if (t == 0) bktTotal[B] = carry;
}

// ---------- scanC: exclusive scan of 391 bucket totals -> bucketBase[392] ----------
__global__ void k_scanC(const unsigned* __restrict__ bktTotal, unsigned* bucketBase) {
    __shared__ unsigned s[256];
    int t = threadIdx.x;
    unsigned carry = 0;
    for (int c0 = 0; c0 < NBKT; c0 += 256) {
        int idx = c0 + t;
        unsigned v = (idx < NBKT) ? bktTotal[idx] : 0;
        s[t] = v; __syncthreads();
        for (int off = 1; off < 256; off <<= 1) {
            unsigned u = (t >= off) ? s[t - off] : 0;
            __syncthreads();
            s[t] += u;
            __syncthreads();
        }
        if (idx < NBKT) bucketBase[idx] = s[t] - v + carry;
        unsigned tot = s[255];
        __syncthreads();
        carry += tot;
    }
    if (t == 0) bucketBase[NBKT] = carry;   // == N_EDGES
}

// ---------- scat1: coarse blocks (4096 edges) -> ~84B/bucket/block, low write-ampl ----
// rec = { (row<<8)|col_local , ea_bits }
__global__ void k_scat1(const int* __restrict__ row, const int* __restrict__ col,
                        const float* __restrict__ ea,
                        const unsigned* __restrict__ histG,
                        const unsigned* __restrict__ bucketBase,
                        int2* __restrict__ recs) {
    __shared__ unsigned base_l[NBKT];
    __shared__ unsigned cursor[NBKT];
    int blk = blockIdx.x, t = threadIdx.x;
    for (int i = t; i < NBKT; i += 512) {
        base_l[i] = bucketBase[i] + histG[(size_t)i * NCHK + blk * 4];
        cursor[i] = 0;
    }
    __syncthreads();
    int e0 = blk * 4096 + t;
#pragma unroll
    for (int k = 0; k < 8; k++) {
        int e = e0 + k * 512;
        if (e < N_EDGES) {
            int c = col[e];
            int bkt = c >> 8;
            unsigned r = atomicAdd(&cursor[bkt], 1u);
            int pos = (int)(base_l[bkt] + r);
            recs[pos] = make_int2((row[e] << 8) | (c & 255), __float_as_int(ea[e]));
        }
    }
}

// ---------- pass2 (fused, 512 thr): count+wsum+scan -> start/cnt/dinv, place csr ----
__global__ void k_pass2(const int2* __restrict__ recs,
                        const unsigned* __restrict__ bucketBase,
                        int* __restrict__ start, int* __restrict__ cnt,
                        float* __restrict__ dinv, int2* __restrict__ csr) {
    __shared__ unsigned cntL[256];
    __shared__ unsigned wsL[256];
    __shared__ unsigned s[256];
    __shared__ int startL[256];
    __shared__ unsigned cur[256];
    int B = blockIdx.x, t = threadIdx.x;
    if (t < 256) { cntL[t] = 0; wsL[t] = 0; cur[t] = 0; }
    __syncthreads();
    int lo = (int)bucketBase[B], hi = (int)bucketBase[B + 1];
    for (int i = lo + t; i < hi; i += 512) {
        int2 rc = recs[i];
        int cl = rc.x & 255;
        atomicAdd(&cntL[cl], 1u);
        unsigned q = __float2uint_rn(__int_as_float(rc.y) * 65536.0f);
        atomicAdd(&wsL[cl], q);
    }
    __syncthreads();
    unsigned v = 0;
    if (t < 256) { v = cntL[t]; s[t] = v; }
    __syncthreads();
    for (int off = 1; off < 256; off <<= 1) {
        unsigned u = 0;
        if (t < 256 && t >= (unsigned)off) u = s[t - off];
        __syncthreads();
        if (t < 256) s[t] += u;
        __syncthreads();
    }
    if (t < 256) {
        int st = lo + (int)(s[t] - v);
        startL[t] = st;
        int node = B * 256 + t;
        if (node < N_NODES) {
            start[node] = st;
            cnt[node] = (int)v;
            dinv[node] = rsqrtf((float)(65536u + wsL[t]) * (1.0f / 65536.0f));
        }
    }
    __syncthreads();
    // phase B: bucket recs are L2-hot (~32 KB); place into final CSR order
    for (int i = lo + t; i < hi; i += 512) {
        int2 rc = recs[i];
        int cl = rc.x & 255;
        int rw = rc.x >> 8;
        unsigned r = atomicAdd(&cur[cl], 1u);
        csr[startL[cl] + (int)r] = make_int2(rw, rc.y);
    }
}

// ---------- k_gemm1: h' = dinv ⊙ (x@W1) (bf16). Wp staged in LDS ----------
__global__ __launch_bounds__(256, 2) void k_gemm1(
        const float* __restrict__ x, const unsigned short* __restrict__ Wp,
        const float* __restrict__ dinv, unsigned short* __restrict__ h) {
    __shared__ unsigned short sWp[32768];            // 64 KB, whole W1 B-frag
    __shared__ unsigned short lds_out[64 * H_DIM];   // 16 KB output staging
    int tid = threadIdx.x;
    int wave = tid >> 6, lane = tid & 63;
    int m = lane & 15, q = lane >> 4;
    int tile = blockIdx.x;
    int row0 = tile * 64 + wave * 16;
    int rowA = row0 + m; if (rowA >= N_NODES) rowA = N_NODES - 1;
    const float* xr = x + (long)rowA * F_INPUT + q * 8;

    float4 xv[16];
#pragma unroll
    for (int ks = 0; ks < 8; ks++) {
        xv[2 * ks]     = *(const float4*)(xr + ks * 32);
        xv[2 * ks + 1] = *(const float4*)(xr + ks * 32 + 4);
    }
#pragma unroll
    for (int it = 0; it < 16; it++) {
        int idx = (it * 256 + tid) * 8;
        *(u16x8*)(sWp + idx) = *(const u16x8*)(Wp + idx);
    }
    __syncthreads();

    f32x4 acc[8];
#pragma unroll
    for (int i = 0; i < 8; i++) acc[i] = (f32x4){0.f, 0.f, 0.f, 0.f};
#pragma unroll
    for (int ks = 0; ks < 8; ks++) {
        float4 a0 = xv[2 * ks], a1 = xv[2 * ks + 1];
        bf8 a;
        a[0] = (short)f2bf(a0.x); a[1] = (short)f2bf(a0.y);
        a[2] = (short)f2bf(a0.z); a[3] = (short)f2bf(a0.w);
        a[4] = (short)f2bf(a1.x); a[5] = (short)f2bf(a1.y);
        a[6] = (short)f2bf(a1.z); a[7] = (short)f2bf(a1.w);
#pragma unroll
        for (int nt = 0; nt < 8; nt++) {
            bf8 bb = *(const bf8*)(sWp + (((nt * 8 + ks) * 64 + lane) << 3));
            acc[nt] = __builtin_amdgcn_mfma_f32_16x16x32_bf16(a, bb, acc[nt], 0, 0, 0);
        }
    }
    int lrow = wave * 16 + q * 4;
    float dv[4];
#pragma unroll
    for (int r = 0; r < 4; r++) {
        int gr = tile * 64 + lrow + r; if (gr >= N_NODES) gr = N_NODES - 1;
        dv[r] = dinv[gr];
    }
#pragma unroll
    for (int nt = 0; nt < 8; nt++)
#pragma unroll
        for (int r = 0; r < 4; r++)
            lds_out[(lrow + r) * H_DIM + nt * 16 + m] = f2bf(acc[nt][r] * dv[r]);
    __syncthreads();
    int valid = N_NODES - tile * 64; if (valid > 64) valid = 64;
    unsigned short* gbase = h + (size_t)tile * 64 * H_DIM;
#pragma unroll
    for (int i = 0; i < 4; i++) {
        int idx = (i * 256 + tid) * 8;
        if (idx < valid * H_DIM)
            *(u16x8*)(gbase + idx) = *(const u16x8*)(lds_out + idx);
    }
}

// ---------- agg1: wave/node, lane owns 2 dims; h pre-scaled, csr w = ea ----------
__global__ __launch_bounds__(256) void k_agg1(
        const unsigned* __restrict__ hw, const int2* __restrict__ csr,
        const int* __restrict__ start, const int* __restrict__ cnt,
        const float* __restrict__ dinv, const float* __restrict__ b1,
        unsigned* __restrict__ h1w) {
    int c = blockIdx.x * 4 + (threadIdx.x >> 6);
    int lane = threadIdx.x & 63;
    if (c >= N_NODES) return;
    float di = dinv[c];
    int su = __builtin_amdgcn_readfirstlane(start[c]);
    int n  = __builtin_amdgcn_readfirstlane(cnt[c]);
    f32x2 acc = bfpair(hw[(size_t)c * 64 + lane]);   // self, weight 1
    int i = 0;
    for (; i + 4 <= n; i += 4) {
        int2 p0 = csr[su + i], p1 = csr[su + i + 1];
        int2 p2 = csr[su + i + 2], p3 = csr[su + i + 3];
        int r0 = __builtin_amdgcn_readfirstlane(p0.x);
        int r1 = __builtin_amdgcn_readfirstlane(p1.x);
        int r2 = __builtin_amdgcn_readfirstlane(p2.x);
        int r3 = __builtin_amdgcn_readfirstlane(p3.x);
        float w0 = __int_as_float(__builtin_amdgcn_readfirstlane(p0.y));
        float w1 = __int_as_float(__builtin_amdgcn_readfirstlane(p1.y));
        float w2 = __int_as_float(__builtin_amdgcn_readfirstlane(p2.y));
        float w3 = __int_as_float(__builtin_amdgcn_readfirstlane(p3.y));
        unsigned a0 = hw[(size_t)r0 * 64 + lane];
        unsigned a1 = hw[(size_t)r1 * 64 + lane];
        unsigned a2 = hw[(size_t)r2 * 64 + lane];
        unsigned a3 = hw[(size_t)r3 * 64 + lane];
        acc += (f32x2){w0, w0} * bfpair(a0);
        acc += (f32x2){w1, w1} * bfpair(a1);
        acc += (f32x2){w2, w2} * bfpair(a2);
        acc += (f32x2){w3, w3} * bfpair(a3);
    }
    for (; i < n; i++) {
        int2 p = csr[su + i];
        int r = __builtin_amdgcn_readfirstlane(p.x);
        float w = __int_as_float(__builtin_amdgcn_readfirstlane(p.y));
        unsigned a = hw[(size_t)r * 64 + lane];
        acc += (f32x2){w, w} * bfpair(a);
    }
    float2 bb = ((const float2*)b1)[lane];
    float o0 = fmaxf(di * acc.x + bb.x, 0.f);
    float o1 = fmaxf(di * acc.y + bb.y, 0.f);
    h1w[(size_t)c * 64 + lane] = (unsigned)f2bf(o0) | ((unsigned)f2bf(o1) << 16);
}

// ---------- GEMM2: h2' = dinv ⊙ (h1 @ W2), bf16, PADDED rows (64 shorts/128B) ----
__global__ __launch_bounds__(256, 4) void k_gemm2(const unsigned short* __restrict__ h1,
                        const unsigned short* __restrict__ Wp,
                        const float* __restrict__ dinv,
                        unsigned short* __restrict__ h2) {
    __shared__ unsigned short lds_out[64 * C_DIM];
    int tid = threadIdx.x;
    int wave = tid >> 6, lane = tid & 63;
    int m = lane & 15, q = lane >> 4;
    int row0 = blockIdx.x * 64 + wave * 16;
    int rowA = row0 + m; if (rowA >= N_NODES) rowA = N_NODES - 1;

    f32x4 acc[3];
#pragma unroll
    for (int i = 0; i < 3; i++) acc[i] = (f32x4){0.f, 0.f, 0.f, 0.f};
    const unsigned short* hr = h1 + (long)rowA * H_DIM + q * 8;
#pragma unroll
    for (int ks = 0; ks < 4; ks++) {
        bf8 a = *(const bf8*)(hr + ks * 32);
#pragma unroll
        for (int nt = 0; nt < 3; nt++) {
            bf8 b = *(const bf8*)(Wp + (((nt * 4 + ks) * 64 + lane) << 3));
            acc[nt] = __builtin_amdgcn_mfma_f32_16x16x32_bf16(a, b, acc[nt], 0, 0, 0);
        }
    }
    int lrow = wave * 16 + q * 4;
    float dv[4];
#pragma unroll
    for (int r = 0; r < 4; r++) {
        int gr = blockIdx.x * 64 + lrow + r; if (gr >= N_NODES) gr = N_NODES - 1;
        dv[r] = dinv[gr];
    }
#pragma unroll
    for (int nt = 0; nt < 3; nt++)
#pragma unroll
        for (int r = 0; r < 4; r++) {
            int colo = nt * 16 + m;
            if (colo < C_DIM)
                lds_out[(lrow + r) * C_DIM + colo] = f2bf(acc[nt][r] * dv[r]);
        }
    __syncthreads();
    int valid = N_NODES - blockIdx.x * 64; if (valid > 64) valid = 64;
    unsigned short* gbase = h2 + (size_t)blockIdx.x * 64 * 64;   // stride 64 shorts
    int total10 = valid * 10;                                     // 10 uint2 per row
    for (int i = tid; i < total10; i += 256) {
        int rw = i / 10, part = i - rw * 10;
        *(uint2*)(gbase + rw * 64 + part * 4) = *(const uint2*)(lds_out + rw * C_DIM + part * 4);
    }
}

// ---------- agg2 + bias + log_softmax: padded h2 (1 line/row), csr w = ea ----------
__global__ void k_agg2(const unsigned short* __restrict__ h2, const int2* __restrict__ csr,
                       const int* __restrict__ start, const int* __restrict__ cnt,
                       const float* __restrict__ dinv, const float* __restrict__ b2,
                       float* __restrict__ out) {
    int c = (blockIdx.x * blockDim.x + threadIdx.x) >> 6;
    int lane = threadIdx.x & 63;
    if (c >= N_NODES) return;
    int eg = lane >> 3, cl = lane & 7;
    float di = dinv[c];
    int s = start[c];
    int n = cnt[c];

    float w[3]; int r[3];
#pragma unroll
    for (int t = 0; t < 3; t++) {
        int i = eg + 8 * t;
        int2 p = csr[s + ((i < n) ? i : 0)];
        bool val = (i < n);
        r[t] = val ? p.x : c;
        w[t] = val ? __int_as_float(p.y) : 0.f;
    }
    uint4 gv[3] = {{0,0,0,0},{0,0,0,0},{0,0,0,0}};
    uint4 selfv = {0, 0, 0, 0};
    if (cl < 5) {
#pragma unroll
        for (int t = 0; t < 3; t++)
            gv[t] = *(const uint4*)(h2 + (long)r[t] * 64 + cl * 8);
        if (eg == 0) selfv = *(const uint4*)(h2 + (long)c * 64 + cl * 8);
    }
    f32x2 acc[4];
#pragma unroll
    for (int k = 0; k < 4; k++) acc[k] = (f32x2){0.f, 0.f};
    {
        unsigned sv[4] = {selfv.x, selfv.y, selfv.z, selfv.w};
        if (eg == 0 && cl < 5)
#pragma unroll
            for (int k = 0; k < 4; k++) acc[k] += bfpair(sv[k]);   // self, weight 1
    }
#pragma unroll
    for (int t = 0; t < 3; t++) {
        unsigned vv[4] = {gv[t].x, gv[t].y, gv[t].z, gv[t].w};
        f32x2 ww = (f32x2){w[t], w[t]};
#pragma unroll
        for (int k = 0; k < 4; k++) acc[k] += ww * bfpair(vv[k]);
    }
    for (int i = 24 + eg; i < n; i += 8) {
        int2 p = csr[s + i];
        if (cl < 5) {
            uint4 v4 = *(const uint4*)(h2 + (long)p.x * 64 + cl * 8);
            unsigned vv[4] = {v4.x, v4.y, v4.z, v4.w};
            float wt = __int_as_float(p.y);
            f32x2 ww = (f32x2){wt, wt};
#pragma unroll
            for (int k = 0; k < 4; k++) acc[k] += ww * bfpair(vv[k]);
        }
    }
#pragma unroll
    for (int k = 0; k < 4; k++) {
        acc[k].x += __shfl_xor(acc[k].x, 8);  acc[k].y += __shfl_xor(acc[k].y, 8);
        acc[k].x += __shfl_xor(acc[k].x, 16); acc[k].y += __shfl_xor(acc[k].y, 16);
        acc[k].x += __shfl_xor(acc[k].x, 32); acc[k].y += __shfl_xor(acc[k].y, 32);
    }
    float v[8];
    float lm = -INFINITY;
    if (cl < 5) {
#pragma unroll
        for (int k = 0; k < 4; k++) {
            v[2 * k]     = di * acc[k].x + b2[cl * 8 + 2 * k];
            v[2 * k + 1] = di * acc[k].y + b2[cl * 8 + 2 * k + 1];
            lm = fmaxf(lm, fmaxf(v[2 * k], v[2 * k + 1]));
        }
    }
    lm = fmaxf(lm, __shfl_xor(lm, 1));
    lm = fmaxf(lm, __shfl_xor(lm, 2));
    lm = fmaxf(lm, __shfl_xor(lm, 4));
    float ls = 0.f;
    if (cl < 5) {
#pragma unroll
        for (int j = 0; j < 8; j++) ls += __expf(v[j] - lm);
    }
    ls += __shfl_xor(ls, 1);
    ls += __shfl_xor(ls, 2);
    ls += __shfl_xor(ls, 4);
    if (eg == 0 && cl < 5) {
        float lsm = lm + logf(ls);
        f32x4 o0, o1;
#pragma unroll
        for (int j = 0; j < 4; j++) { o0[j] = v[j] - lsm; o1[j] = v[j + 4] - lsm; }
        *(f32x4*)(out + (long)c * C_DIM + cl * 8)     = o0;
        *(f32x4*)(out + (long)c * C_DIM + cl * 8 + 4) = o1;
    }
}

extern "C" void kernel_launch(void* const* d_in, const int* in_sizes, int n_in,
                              void* d_out, int out_size, void* d_ws, size_t ws_size,
                              hipStream_t stream) {
    const float* x  = (const float*)d_in[0];
    const int*   ei = (const int*)d_in[1];
    const float* ea = (const float*)d_in[2];
    const float* W1 = (const float*)d_in[3];
    const float* b1 = (const float*)d_in[4];
    const float* W2 = (const float*)d_in[5];
    const float* b2 = (const float*)d_in[6];
    const int* row = ei;
    const int* col = ei + N_EDGES;

    char* ws = (char*)d_ws;
    size_t off = 0;
    auto alloc = [&](size_t bytes) -> void* {
        void* p = ws + off;
        off = (off + bytes + 255) & ~(size_t)255;
        return p;
    };
    unsigned*       histG   = (unsigned*)alloc((size_t)NBKT * NCHK * 4);  // 2.4 MB
    unsigned*       bktTot  = (unsigned*)alloc((size_t)NBKT * 4);
    unsigned*       bktBase = (unsigned*)alloc((size_t)(NBKT + 1) * 4);
    int*            start   = (int*)alloc((size_t)N_NODES * 4);
    int*            cnt     = (int*)alloc((size_t)N_NODES * 4);
    float*          dinv    = (float*)alloc((size_t)N_NODES * 4);
    int2*           recs    = (int2*)alloc((size_t)N_EDGES * 8);
    int2*           csr     = (int2*)alloc((size_t)(N_EDGES + 8) * 8); // +pad, NOT last
    unsigned short* Wp1     = (unsigned short*)alloc(32768 * 2);
    unsigned short* Wp2     = (unsigned short*)alloc(6144 * 2);
    unsigned short* h       = (unsigned short*)alloc((size_t)(N_NODES + 64) * H_DIM * 2);
    unsigned short* h1      = (unsigned short*)alloc((size_t)N_NODES * H_DIM * 2);
    unsigned short* h2      = (unsigned short*)alloc((size_t)(N_NODES + 64) * 64 * 2); // padded

    k_preh<<<NPREB + NCHK, 256, 0, stream>>>(W1, W2, Wp1, Wp2, col, histG);
    k_scanB<<<NBKT, 256, 0, stream>>>(histG, bktTot);
    k_scanC<<<1, 256, 0, stream>>>(bktTot, bktBase);
    k_scat1<<<NSC1, 512, 0, stream>>>(row, col, ea, histG, bktBase, recs);
    k_pass2<<<NBKT, 512, 0, stream>>>(recs, bktBase, start, cnt, dinv, csr);
    k_gemm1<<<NGEMM1, 256, 0, stream>>>(x, Wp1, dinv, h);
    k_agg1<<<N_NODES / 4, 256, 0, stream>>>((const unsigned*)h, csr, start, cnt, dinv, b1,
                                            (unsigned*)h1);
    k_gemm2<<<(N_NODES + 63) / 64, 256, 0, stream>>>(h1, Wp2, dinv, h2);
    k_agg2<<<N_NODES / 4, 256, 0, stream>>>(h2, csr, start, cnt, dinv, b2, (float*)d_out);
}